// Round 5
// baseline (1017.823 us; speedup 1.0000x reference)
//
#include <hip/hip_runtime.h>
#include <hip/hip_bf16.h>

// Problem constants
#define NB 8
#define NS 2048
#define ND 768
#define NH 8
#define NHD 96
#define ATTN_SCALE 0.1020620726159658f   // 1/sqrt(96)
#define LOG2E 1.4426950408889634f
#define QSCALE (ATTN_SCALE * LOG2E)      // folded into Q so probs = exp2(s)

#define NX (NB * NS * ND)                // 12,582,912 feature elems
#define NW (ND * ND)                     // 589,824 per weight

typedef short sh8 __attribute__((ext_vector_type(8)));   // 8 bf16 = 4 VGPRs (MFMA A/B frag)
typedef float f4  __attribute__((ext_vector_type(4)));   // MFMA C/D frag

__device__ __forceinline__ unsigned int pack_bf2(float a, float b) {
    __hip_bfloat162 h = __float22bfloat162_rn(make_float2(a, b));
    return *reinterpret_cast<unsigned int*>(&h);
}

__device__ __forceinline__ void async16(const void* g, void* l) {
    __builtin_amdgcn_global_load_lds(
        (const __attribute__((address_space(1))) unsigned int*)g,
        (__attribute__((address_space(3))) unsigned int*)l, 16, 0, 0);
}

// ---------------------------------------------------------------------------
// Kernel 0: convert X (fp32) and Wq/Wk/Wv (fp32) to bf16.
// Xb/Wb live in d_out (overwritten later by attn -- safe). 8 elems/thread.
// ---------------------------------------------------------------------------
__global__ __launch_bounds__(256) void cvt_bf16(
    const float* __restrict__ X, const float* __restrict__ Wq,
    const float* __restrict__ Wk, const float* __restrict__ Wv,
    __hip_bfloat16* __restrict__ Xb, __hip_bfloat16* __restrict__ Wb)
{
    const long long i8 = ((long long)blockIdx.x * 256 + threadIdx.x) * 8;
    const float* src; __hip_bfloat16* dst; long long off;
    if (i8 < NX) { src = X; dst = Xb; off = i8; }
    else {
        const long long j = i8 - NX;
        const int w = (int)(j / NW);
        off = j - (long long)w * NW;
        src = (w == 0) ? Wq : (w == 1) ? Wk : Wv;
        dst = Wb + (long long)w * NW;
    }
    const float4 a = *(const float4*)&src[off];
    const float4 b = *(const float4*)&src[off + 4];
    const uint4 o = make_uint4(pack_bf2(a.x, a.y), pack_bf2(a.z, a.w),
                               pack_bf2(b.x, b.y), pack_bf2(b.z, b.w));
    *(uint4*)&dst[off] = o;
}

// ---------------------------------------------------------------------------
// Kernel 1: QKV projection, m97-style: 128x128 tile, BK=64, global_load_lds
// width-16 staging, bf16 MFMA. 256 threads = 4 waves in 2x2.
// z: 0=Q (scaled by QSCALE, [B,H,S,HD]), 1=K ([B,H,S,HD]), 2=V^T ([B,H,HD,S]).
// For z in {0,1} the MFMA operands are SWAPPED (A=W, B=X) so each lane's
// C column holds 4 consecutive hd at fixed s -> packed 8B stores.
// ---------------------------------------------------------------------------
__global__ __launch_bounds__(256) void qkv_mfma(
    const __hip_bfloat16* __restrict__ Xb, const __hip_bfloat16* __restrict__ Wb,
    const float* __restrict__ bq, const float* __restrict__ bk,
    const float* __restrict__ bv,
    __hip_bfloat16* __restrict__ Qo, __hip_bfloat16* __restrict__ Ko,
    __hip_bfloat16* __restrict__ Vo)
{
    __shared__ unsigned short As[128 * 64];  // X tile [m][k] flat (async dest)
    __shared__ unsigned short Bs[128 * 64];  // W tile [n][k] flat

    const int z = blockIdx.z;
    const __hip_bfloat16* W = Wb + (size_t)z * NW;
    const float* bias = (z == 0) ? bq : (z == 1) ? bk : bv;

    const int tid  = threadIdx.x;
    const int w    = tid >> 6;
    const int lane = tid & 63;
    const int quad = lane >> 4;
    const int nl   = lane & 15;
    const int wm = w >> 1, wn = w & 1;
    const int m0 = blockIdx.y << 7;
    const int n0 = blockIdx.x << 7;

    const bool swapped = (z != 2);

    const f4 zero4 = {0.f, 0.f, 0.f, 0.f};
    f4 acc[4][4];
    #pragma unroll
    for (int i = 0; i < 4; ++i)
        #pragma unroll
        for (int j = 0; j < 4; ++j) acc[i][j] = zero4;

    for (int k0 = 0; k0 < ND; k0 += 64) {
        // Stage A,B: 1024 chunks of 16B each; 4 issues x 4 waves x 64 lanes.
        #pragma unroll
        for (int i = 0; i < 4; ++i) {
            const int cb = (i << 8) + (w << 6);      // wave-uniform chunk base
            const int c  = cb + lane;
            const int row = c >> 3, col = (c & 7) << 3;
            async16(&Xb[(size_t)(m0 + row) * ND + k0 + col], &As[(size_t)cb << 3]);
            async16(&W [(size_t)(n0 + row) * ND + k0 + col], &Bs[(size_t)cb << 3]);
        }
        __syncthreads();   // drains vmcnt -> staging visible

        // Fragment sources: swapped -> A from W tile, B from X tile.
        const unsigned short* Arow = swapped ? Bs : As;
        const unsigned short* Brow = swapped ? As : Bs;
        sh8 af[4][2], bfr[4][2];
        #pragma unroll
        for (int t = 0; t < 4; ++t)
            #pragma unroll
            for (int kc = 0; kc < 2; ++kc) {
                af[t][kc]  = *(const sh8*)&Arow[((wm << 6) + (t << 4) + nl) * 64 + (kc << 5) + (quad << 3)];
                bfr[t][kc] = *(const sh8*)&Brow[((wn << 6) + (t << 4) + nl) * 64 + (kc << 5) + (quad << 3)];
            }
        #pragma unroll
        for (int mt = 0; mt < 4; ++mt)
            #pragma unroll
            for (int nt = 0; nt < 4; ++nt)
                #pragma unroll
                for (int kc = 0; kc < 2; ++kc)
                    acc[mt][nt] = __builtin_amdgcn_mfma_f32_16x16x32_bf16(
                        af[mt][kc], bfr[nt][kc], acc[mt][nt], 0, 0, 0);
        __syncthreads();
    }

    // Epilogue. C layout per 16x16 tile: row = quad*4+r, col = nl.
    if (swapped) {
        // C[n][m]: rows are n (hd side), cols are m (s side).
        __hip_bfloat16* Out = (z == 0) ? Qo : Ko;
        const float sc = (z == 0) ? QSCALE : 1.0f;
        #pragma unroll
        for (int mt = 0; mt < 4; ++mt) {
            const int nb = n0 + (wm << 6) + (mt << 4) + (quad << 2);  // 4-aligned
            const int hh = nb / NHD, hd0 = nb % NHD;  // run of 4 stays in-head
            const float4 bn = *(const float4*)&bias[nb];
            #pragma unroll
            for (int nt = 0; nt < 4; ++nt) {
                const int m = m0 + (wn << 6) + (nt << 4) + nl;
                const int bb = m >> 11;
                const int s  = m & (NS - 1);
                const f4 a = acc[mt][nt];
                const uint2 pk = make_uint2(
                    pack_bf2((a[0] + bn.x) * sc, (a[1] + bn.y) * sc),
                    pack_bf2((a[2] + bn.z) * sc, (a[3] + bn.w) * sc));
                *(uint2*)&Out[((size_t)(bb * NH + hh) * NS + s) * NHD + hd0] = pk;
            }
        }
    } else {
        // C[m][n]: rows are m (s side), cols are n (hd side). V^T store.
        #pragma unroll
        for (int mt = 0; mt < 4; ++mt) {
            const int mb = m0 + (wm << 6) + (mt << 4) + (quad << 2);
            const int bb = mb >> 11;
            const int s0 = mb & (NS - 1);
            #pragma unroll
            for (int nt = 0; nt < 4; ++nt) {
                const int n = n0 + (wn << 6) + (nt << 4) + nl;
                const int hh = n / NHD, hd = n % NHD;
                const float bn = bias[n];
                const f4 a = acc[mt][nt];
                const uint2 pk = make_uint2(pack_bf2(a[0] + bn, a[1] + bn),
                                            pack_bf2(a[2] + bn, a[3] + bn));
                *(uint2*)&Vo[((size_t)(bb * NH + hh) * NHD + hd) * NS + s0] = pk;
            }
        }
    }
}

// ---------------------------------------------------------------------------
// Kernel 2: MFMA flash attention + residual, prefetched, no-max softmax.
// Block = (b, h, 64-q tile), 4 waves; wave w owns q rows w*16..+15.
// __launch_bounds__(256, 3): LDS caps occupancy at 3 blocks/CU anyway, so
// allow ~170 VGPRs -- the default (~112 cap) spilled the K/V prefetch regs
// to scratch (R3/R4: ~900 MB of HBM write traffic).
// ---------------------------------------------------------------------------
__global__ __launch_bounds__(256, 3) void attn_mfma(
    const __hip_bfloat16* __restrict__ Qg, const __hip_bfloat16* __restrict__ Kg,
    const __hip_bfloat16* __restrict__ Vtg, const int* __restrict__ adj,
    const float* __restrict__ features, float* __restrict__ out)
{
    __shared__ unsigned short Ks[64][104];  // [kv][d], padded (stride 208B)
    __shared__ unsigned short Vs[96][72];   // [d][kv], padded (stride 144B)
    __shared__ float Ps[64][64];            // fp32, XOR-swizzled 4-dword groups

    const int tid  = threadIdx.x;
    const int w    = tid >> 6;
    const int lane = tid & 63;
    const int quad = lane >> 4;
    const int nl   = lane & 15;
    const int qt = blockIdx.x, h = blockIdx.y, b = blockIdx.z;
    const int sq0 = qt << 6;

    const size_t bh = (size_t)b * NH + h;
    const __hip_bfloat16* Qbase = Qg + (bh * NS + sq0) * NHD;
    const __hip_bfloat16* Kbase = Kg + bh * NS * NHD;
    const __hip_bfloat16* Vbase = Vtg + bh * NHD * NS;    // V^T: [hd][s]
    const int* adjbase = adj + ((size_t)b * NS + sq0) * NS;

    // Staging coordinates (loop-invariant)
    int krow[3], kc8[3], vrow[3], vc8[3];
    #pragma unroll
    for (int i = 0; i < 3; ++i) {
        const int f = tid + (i << 8);
        krow[i] = f / 12; kc8[i] = f % 12;
        vrow[i] = f >> 3; vc8[i] = f & 7;
    }

    // Q fragments (A-operand), pre-scaled by QSCALE at projection
    sh8 qf[3];
    #pragma unroll
    for (int kc = 0; kc < 3; ++kc)
        qf[kc] = *(const sh8*)&Qbase[(size_t)((w << 4) + nl) * NHD + kc * 32 + (quad << 3)];

    const f4 zero4 = {0.f, 0.f, 0.f, 0.f};
    f4 o[6];
    float l_acc[4];
    #pragma unroll
    for (int t = 0; t < 6; ++t) o[t] = zero4;
    #pragma unroll
    for (int r = 0; r < 4; ++r) l_acc[r] = 0.f;

    // Preload tile kt=0 into regs
    uint4 kr[3], vr[3];
    #pragma unroll
    for (int i = 0; i < 3; ++i) {
        kr[i] = *(const uint4*)&Kbase[(size_t)krow[i] * NHD + (kc8[i] << 3)];
        vr[i] = *(const uint4*)&Vbase[(size_t)vrow[i] * NS + (vc8[i] << 3)];
    }

    for (int kt = 0; kt < 32; ++kt) {
        const int sk0 = kt << 6;

        // Commit prefetched K/V regs to LDS
        #pragma unroll
        for (int i = 0; i < 3; ++i) {
            *(uint4*)&Ks[krow[i]][kc8[i] << 3] = kr[i];
            *(uint4*)&Vs[vrow[i]][vc8[i] << 3] = vr[i];
        }
        __syncthreads();   // (a) staging visible

        // Prefetch next tile (WAR on kr/vr is safe: ds_write consumed them)
        if (kt < 31) {
            const int skn = sk0 + 64;
            #pragma unroll
            for (int i = 0; i < 3; ++i) {
                kr[i] = *(const uint4*)&Kbase[(size_t)(skn + krow[i]) * NHD + (kc8[i] << 3)];
                vr[i] = *(const uint4*)&Vbase[(size_t)vrow[i] * NS + skn + (vc8[i] << 3)];
            }
        }

        // Adjacency for this tile (overlaps the QK MFMAs below)
        int am[4][4];
        #pragma unroll
        for (int ct = 0; ct < 4; ++ct)
            #pragma unroll
            for (int r = 0; r < 4; ++r)
                am[ct][r] = adjbase[(size_t)((w << 4) + (quad << 2) + r) * NS +
                                    sk0 + (ct << 4) + nl];

        // Scores: 16 q x 64 kv per wave
        f4 sc[4];
        #pragma unroll
        for (int ct = 0; ct < 4; ++ct) sc[ct] = zero4;
        #pragma unroll
        for (int ct = 0; ct < 4; ++ct)
            #pragma unroll
            for (int kc = 0; kc < 3; ++kc) {
                const sh8 kf = *(const sh8*)&Ks[(ct << 4) + nl][kc * 32 + (quad << 3)];
                sc[ct] = __builtin_amdgcn_mfma_f32_16x16x32_bf16(qf[kc], kf, sc[ct], 0, 0, 0);
            }

        // No-max softmax: p = adj ? 2^s : 0  (s pre-scaled by log2e/sqrt(hd))
        float pr[4][4];
        #pragma unroll
        for (int ct = 0; ct < 4; ++ct)
            #pragma unroll
            for (int r = 0; r < 4; ++r)
                pr[ct][r] = am[ct][r] ? __builtin_amdgcn_exp2f(sc[ct][r]) : 0.f;
        #pragma unroll
        for (int r = 0; r < 4; ++r)
            l_acc[r] += (pr[0][r] + pr[1][r]) + (pr[2][r] + pr[3][r]);

        // Write P (wave-private rows), XOR-swizzled
        const int rowbase = (w << 4) + (quad << 2);
        #pragma unroll
        for (int ct = 0; ct < 4; ++ct) {
            const int g = (ct << 2) + (nl >> 2);
            const int off = nl & 3;
            #pragma unroll
            for (int r = 0; r < 4; ++r) {
                const int rm = (quad << 2) + r;
                Ps[rowbase + r][((g ^ rm) << 2) | off] = pr[ct][r];
            }
        }
        // No barrier: wave w reads back only its own rows (lgkmcnt-ordered)

        sh8 pf[2];
        #pragma unroll
        for (int kc2 = 0; kc2 < 2; ++kc2) {
            const int g0 = (kc2 << 3) + (quad << 1);
            const f4 lo = *(const f4*)&Ps[(w << 4) + nl][((g0 ^ nl) << 2)];
            const f4 hi = *(const f4*)&Ps[(w << 4) + nl][(((g0 + 1) ^ nl) << 2)];
            union { uint4 u; sh8 s; } pu;
            pu.u = make_uint4(pack_bf2(lo[0], lo[1]), pack_bf2(lo[2], lo[3]),
                              pack_bf2(hi[0], hi[1]), pack_bf2(hi[2], hi[3]));
            pf[kc2] = pu.s;
        }

        // PV: O[16 q][96 hd] += P[16][64] @ V[64][96]
        #pragma unroll
        for (int t = 0; t < 6; ++t)
            #pragma unroll
            for (int kc2 = 0; kc2 < 2; ++kc2) {
                const sh8 vf = *(const sh8*)&Vs[(t << 4) + nl][(kc2 << 5) + (quad << 3)];
                o[t] = __builtin_amdgcn_mfma_f32_16x16x32_bf16(pf[kc2], vf, o[t], 0, 0, 0);
            }
        __syncthreads();   // (c) done reading Ks/Vs before next commit
    }

    // Deferred l reduction (over the 16 nl lanes of each row)
    float inv[4];
    #pragma unroll
    for (int r = 0; r < 4; ++r) {
        float l = l_acc[r];
        l += __shfl_xor(l, 1);
        l += __shfl_xor(l, 2);
        l += __shfl_xor(l, 4);
        l += __shfl_xor(l, 8);
        inv[r] = 1.0f / l;
    }

    // Epilogue: O/l + residual
    #pragma unroll
    for (int r = 0; r < 4; ++r) {
        const int srow = sq0 + (w << 4) + (quad << 2) + r;
        const size_t base = ((size_t)b * NS + srow) * ND + h * NHD;
        #pragma unroll
        for (int t = 0; t < 6; ++t) {
            const int d = (t << 4) + nl;
            out[base + d] = o[t][r] * inv[r] + features[base + d];
        }
    }
}

// ---------------------------------------------------------------------------
// Kernel 3: in-place LayerNorm over last dim (768). One wave per row.
// ---------------------------------------------------------------------------
__global__ __launch_bounds__(256) void ln_kernel(
    float* __restrict__ out, const float* __restrict__ gamma,
    const float* __restrict__ beta)
{
    const int row = (blockIdx.x << 2) + (threadIdx.x >> 6);
    const int lane = threadIdx.x & 63;
    float* p = out + (size_t)row * ND;

    float4 v[3];
    float s = 0.f, sq = 0.f;
    #pragma unroll
    for (int i = 0; i < 3; ++i) {
        v[i] = *(const float4*)&p[(i << 8) + (lane << 2)];
        s += v[i].x + v[i].y + v[i].z + v[i].w;
        sq += v[i].x * v[i].x + v[i].y * v[i].y + v[i].z * v[i].z + v[i].w * v[i].w;
    }
    #pragma unroll
    for (int off = 32; off; off >>= 1) {
        s += __shfl_xor(s, off);
        sq += __shfl_xor(sq, off);
    }
    const float mu = s * (1.0f / ND);
    const float var = sq * (1.0f / ND) - mu * mu;
    const float rs = rsqrtf(var + 1e-5f);
    #pragma unroll
    for (int i = 0; i < 3; ++i) {
        const int d = (i << 8) + (lane << 2);
        const float4 g = *(const float4*)&gamma[d];
        const float4 be = *(const float4*)&beta[d];
        float4 ov;
        ov.x = (v[i].x - mu) * rs * g.x + be.x;
        ov.y = (v[i].y - mu) * rs * g.y + be.y;
        ov.z = (v[i].z - mu) * rs * g.z + be.z;
        ov.w = (v[i].w - mu) * rs * g.w + be.w;
        *(float4*)&p[d] = ov;
    }
}

// ---------------------------------------------------------------------------
extern "C" void kernel_launch(void* const* d_in, const int* in_sizes, int n_in,
                              void* d_out, int out_size, void* d_ws, size_t ws_size,
                              hipStream_t stream) {
    (void)in_sizes; (void)n_in; (void)out_size; (void)ws_size;

    const float* features = (const float*)d_in[0];
    const int*   adj      = (const int*)d_in[1];
    const float* Wq       = (const float*)d_in[2];
    const float* bq       = (const float*)d_in[3];
    const float* Wk       = (const float*)d_in[4];
    const float* bk       = (const float*)d_in[5];
    const float* Wv       = (const float*)d_in[6];
    const float* bv       = (const float*)d_in[7];
    const float* gamma    = (const float*)d_in[8];
    const float* beta     = (const float*)d_in[9];
    float* out = (float*)d_out;

    // bf16 X and W live in d_out (fully overwritten later by attn+ln).
    __hip_bfloat16* Xb = (__hip_bfloat16*)d_out;
    __hip_bfloat16* Wb = Xb + (size_t)NX;
    // Q/K/V bf16 in workspace (V stored transposed [B,H,HD,S]).
    __hip_bfloat16* Qb = (__hip_bfloat16*)d_ws;
    __hip_bfloat16* Kb = Qb + (size_t)NX;
    __hip_bfloat16* Vb = Kb + (size_t)NX;

    // 0) fp32 -> bf16 convert (X + 3 weights)
    cvt_bf16<<<(NX + 3 * NW) / (8 * 256), 256, 0, stream>>>(
        features, Wq, Wk, Wv, Xb, Wb);

    // 1) QKV projections: grid (N/128, M/128, 3)
    dim3 g1(ND / 128, (NB * NS) / 128, 3);
    qkv_mfma<<<g1, 256, 0, stream>>>(Xb, Wb, bq, bk, bv, Qb, Kb, Vb);

    // 2) MFMA flash attention + residual: grid (S/64, H, B)
    dim3 g2(NS / 64, NH, NB);
    attn_mfma<<<g2, 256, 0, stream>>>(Qb, Kb, Vb, adj, features, out);

    // 3) LayerNorm in place
    ln_kernel<<<(NB * NS) / 4, 256, 0, stream>>>(out, gamma, beta);
}

// Round 6
// 743.315 us; speedup vs baseline: 1.3693x; 1.3693x over previous
//
#include <hip/hip_runtime.h>
#include <hip/hip_bf16.h>

// Problem constants
#define NB 8
#define NS 2048
#define ND 768
#define NH 8
#define NHD 96
#define ATTN_SCALE 0.1020620726159658f   // 1/sqrt(96)
#define LOG2E 1.4426950408889634f
#define QSCALE (ATTN_SCALE * LOG2E)      // folded into Q so probs = exp2(s)

#define NX (NB * NS * ND)                // 12,582,912 feature elems
#define NW (ND * ND)                     // 589,824 per weight

typedef short sh8 __attribute__((ext_vector_type(8)));   // 8 bf16 = 4 VGPRs (MFMA A/B frag)
typedef float f4  __attribute__((ext_vector_type(4)));   // MFMA C/D frag

__device__ __forceinline__ unsigned int pack_bf2(float a, float b) {
    __hip_bfloat162 h = __float22bfloat162_rn(make_float2(a, b));
    return *reinterpret_cast<unsigned int*>(&h);
}

__device__ __forceinline__ unsigned short f2bf(float a) {
    __hip_bfloat16 h = __float2bfloat16(a);
    return *reinterpret_cast<unsigned short*>(&h);
}

__device__ __forceinline__ void async16(const void* g, void* l) {
    __builtin_amdgcn_global_load_lds(
        (const __attribute__((address_space(1))) unsigned int*)g,
        (__attribute__((address_space(3))) unsigned int*)l, 16, 0, 0);
}

// ---------------------------------------------------------------------------
// Kernel 0: convert X (fp32) and Wq/Wk/Wv (fp32) to bf16.
// Xb/Wb live in d_out (overwritten later by attn -- safe). 8 elems/thread.
// ---------------------------------------------------------------------------
__global__ __launch_bounds__(256) void cvt_bf16(
    const float* __restrict__ X, const float* __restrict__ Wq,
    const float* __restrict__ Wk, const float* __restrict__ Wv,
    __hip_bfloat16* __restrict__ Xb, __hip_bfloat16* __restrict__ Wb)
{
    const long long i8 = ((long long)blockIdx.x * 256 + threadIdx.x) * 8;
    const float* src; __hip_bfloat16* dst; long long off;
    if (i8 < NX) { src = X; dst = Xb; off = i8; }
    else {
        const long long j = i8 - NX;
        const int w = (int)(j / NW);
        off = j - (long long)w * NW;
        src = (w == 0) ? Wq : (w == 1) ? Wk : Wv;
        dst = Wb + (long long)w * NW;
    }
    const float4 a = *(const float4*)&src[off];
    const float4 b = *(const float4*)&src[off + 4];
    const uint4 o = make_uint4(pack_bf2(a.x, a.y), pack_bf2(a.z, a.w),
                               pack_bf2(b.x, b.y), pack_bf2(b.z, b.w));
    *(uint4*)&dst[off] = o;
}

// ---------------------------------------------------------------------------
// Kernel 1: QKV projection, m97-style: 128x128 tile, BK=64, global_load_lds
// width-16 staging, bf16 MFMA. 256 threads = 4 waves in 2x2.
// z: 0=Q (scaled by QSCALE, [B,H,S,HD]), 1=K ([B,H,S,HD]), 2=V^T ([B,H,HD,S]).
// For z in {0,1} the MFMA operands are SWAPPED (A=W, B=X) so each lane's
// C column holds 4 consecutive hd at fixed s -> packed 8B stores.
// ---------------------------------------------------------------------------
__global__ __launch_bounds__(256) void qkv_mfma(
    const __hip_bfloat16* __restrict__ Xb, const __hip_bfloat16* __restrict__ Wb,
    const float* __restrict__ bq, const float* __restrict__ bk,
    const float* __restrict__ bv,
    __hip_bfloat16* __restrict__ Qo, __hip_bfloat16* __restrict__ Ko,
    __hip_bfloat16* __restrict__ Vo)
{
    __shared__ unsigned short As[128 * 64];  // X tile [m][k] flat (async dest)
    __shared__ unsigned short Bs[128 * 64];  // W tile [n][k] flat

    const int z = blockIdx.z;
    const __hip_bfloat16* W = Wb + (size_t)z * NW;
    const float* bias = (z == 0) ? bq : (z == 1) ? bk : bv;

    const int tid  = threadIdx.x;
    const int w    = tid >> 6;
    const int lane = tid & 63;
    const int quad = lane >> 4;
    const int nl   = lane & 15;
    const int wm = w >> 1, wn = w & 1;
    const int m0 = blockIdx.y << 7;
    const int n0 = blockIdx.x << 7;

    const bool swapped = (z != 2);

    const f4 zero4 = {0.f, 0.f, 0.f, 0.f};
    f4 acc[4][4];
    #pragma unroll
    for (int i = 0; i < 4; ++i)
        #pragma unroll
        for (int j = 0; j < 4; ++j) acc[i][j] = zero4;

    for (int k0 = 0; k0 < ND; k0 += 64) {
        // Stage A,B: 1024 chunks of 16B each; 4 issues x 4 waves x 64 lanes.
        #pragma unroll
        for (int i = 0; i < 4; ++i) {
            const int cb = (i << 8) + (w << 6);      // wave-uniform chunk base
            const int c  = cb + lane;
            const int row = c >> 3, col = (c & 7) << 3;
            async16(&Xb[(size_t)(m0 + row) * ND + k0 + col], &As[(size_t)cb << 3]);
            async16(&W [(size_t)(n0 + row) * ND + k0 + col], &Bs[(size_t)cb << 3]);
        }
        __syncthreads();   // drains vmcnt -> staging visible

        // Fragment sources: swapped -> A from W tile, B from X tile.
        const unsigned short* Arow = swapped ? Bs : As;
        const unsigned short* Brow = swapped ? As : Bs;
        sh8 af[4][2], bfr[4][2];
        #pragma unroll
        for (int t = 0; t < 4; ++t)
            #pragma unroll
            for (int kc = 0; kc < 2; ++kc) {
                af[t][kc]  = *(const sh8*)&Arow[((wm << 6) + (t << 4) + nl) * 64 + (kc << 5) + (quad << 3)];
                bfr[t][kc] = *(const sh8*)&Brow[((wn << 6) + (t << 4) + nl) * 64 + (kc << 5) + (quad << 3)];
            }
        #pragma unroll
        for (int mt = 0; mt < 4; ++mt)
            #pragma unroll
            for (int nt = 0; nt < 4; ++nt)
                #pragma unroll
                for (int kc = 0; kc < 2; ++kc)
                    acc[mt][nt] = __builtin_amdgcn_mfma_f32_16x16x32_bf16(
                        af[mt][kc], bfr[nt][kc], acc[mt][nt], 0, 0, 0);
        __syncthreads();
    }

    // Epilogue. C layout per 16x16 tile: row = quad*4+r, col = nl.
    if (swapped) {
        // C[n][m]: rows are n (hd side), cols are m (s side).
        __hip_bfloat16* Out = (z == 0) ? Qo : Ko;
        const float sc = (z == 0) ? QSCALE : 1.0f;
        #pragma unroll
        for (int mt = 0; mt < 4; ++mt) {
            const int nb = n0 + (wm << 6) + (mt << 4) + (quad << 2);  // 4-aligned
            const int hh = nb / NHD, hd0 = nb % NHD;  // run of 4 stays in-head
            const float4 bn = *(const float4*)&bias[nb];
            #pragma unroll
            for (int nt = 0; nt < 4; ++nt) {
                const int m = m0 + (wn << 6) + (nt << 4) + nl;
                const int bb = m >> 11;
                const int s  = m & (NS - 1);
                const f4 a = acc[mt][nt];
                const uint2 pk = make_uint2(
                    pack_bf2((a[0] + bn.x) * sc, (a[1] + bn.y) * sc),
                    pack_bf2((a[2] + bn.z) * sc, (a[3] + bn.w) * sc));
                *(uint2*)&Out[((size_t)(bb * NH + hh) * NS + s) * NHD + hd0] = pk;
            }
        }
    } else {
        // C[m][n]: rows are m (s side), cols are n (hd side). V^T store.
        #pragma unroll
        for (int mt = 0; mt < 4; ++mt) {
            const int mb = m0 + (wm << 6) + (mt << 4) + (quad << 2);
            const int bb = mb >> 11;
            const int s0 = mb & (NS - 1);
            #pragma unroll
            for (int nt = 0; nt < 4; ++nt) {
                const int n = n0 + (wn << 6) + (nt << 4) + nl;
                const int hh = n / NHD, hd = n % NHD;
                const float bn = bias[n];
                const f4 a = acc[mt][nt];
                const uint2 pk = make_uint2(pack_bf2(a[0] + bn, a[1] + bn),
                                            pack_bf2(a[2] + bn, a[3] + bn));
                *(uint2*)&Vo[((size_t)(bb * NH + hh) * NHD + hd) * NS + s0] = pk;
            }
        }
    }
}

// ---------------------------------------------------------------------------
// Kernel 2: MFMA flash attention + residual.
//  - K tile: double-buffered UNPADDED LDS [2][64][96], staged by
//    global_load_lds (K's global tile is a contiguous 12288B span = linear
//    match; zero staging registers, prefetch drained at the end barrier).
//  - V tile: register-staged into padded [96][72] (repack from [hd][S]).
//  - P: bf16 LDS [64][72]; b16 writes + direct sh8 A-frag reads, both 2-way.
//  - adj loaded per current tile, issued OLDEST so its mid-iter vmcnt wait
//    does not drain the V/K prefetch (vmcnt is FIFO).
//  - no-max softmax (Q pre-scaled by log2e/sqrt(hd)); l deferred to epilogue.
//  Plain launch bounds: R5's (256,3) made the allocator squeeze to 76 VGPR
//  and spill 1.36 GB. Target liveness here is ~100 regs.
// ---------------------------------------------------------------------------
__global__ __launch_bounds__(256) void attn_mfma(
    const __hip_bfloat16* __restrict__ Qg, const __hip_bfloat16* __restrict__ Kg,
    const __hip_bfloat16* __restrict__ Vtg, const int* __restrict__ adj,
    const float* __restrict__ features, float* __restrict__ out)
{
    __shared__ unsigned short Ks[2][64][96];  // unpadded: async16 image, dbuf
    __shared__ unsigned short Vs[96][72];     // [d][kv], padded (144B rows)
    __shared__ unsigned short Pb[64][72];     // P bf16, padded (144B rows)

    const int tid  = threadIdx.x;
    const int w    = tid >> 6;
    const int lane = tid & 63;
    const int quad = lane >> 4;
    const int nl   = lane & 15;
    const int qt = blockIdx.x, h = blockIdx.y, b = blockIdx.z;
    const int sq0 = qt << 6;

    const size_t bh = (size_t)b * NH + h;
    const __hip_bfloat16* Qbase = Qg + (bh * NS + sq0) * NHD;
    const __hip_bfloat16* Kbase = Kg + bh * NS * NHD;   // [s][hd], tile-linear
    const __hip_bfloat16* Vbase = Vtg + bh * NHD * NS;  // V^T: [hd][s]
    const int* adjbase = adj + ((size_t)b * NS + sq0) * NS;

    // V staging coords (loop-invariant): 768 chunks = 96 rows x 8
    int vrow[3], vc8[3];
    #pragma unroll
    for (int i = 0; i < 3; ++i) {
        const int f = tid + (i << 8);
        vrow[i] = f >> 3; vc8[i] = f & 7;
    }

    // Q fragments (A-operand), pre-scaled by QSCALE at projection
    sh8 qf[3];
    #pragma unroll
    for (int kc = 0; kc < 3; ++kc)
        qf[kc] = *(const sh8*)&Qbase[(size_t)((w << 4) + nl) * NHD + kc * 32 + (quad << 3)];

    const f4 zero4 = {0.f, 0.f, 0.f, 0.f};
    f4 o[6];
    float l_acc[4];
    #pragma unroll
    for (int t = 0; t < 6; ++t) o[t] = zero4;
    #pragma unroll
    for (int r = 0; r < 4; ++r) l_acc[r] = 0.f;

    // Preloop: async K(0) -> Ks[0]; sync-preload V(0) into regs.
    #pragma unroll
    for (int i = 0; i < 3; ++i) {
        const int cb = (i << 8) + (w << 6);   // wave-uniform chunk base
        async16(&Kbase[(size_t)(cb + lane) << 3], &Ks[0][0][(size_t)cb << 3]);
    }
    uint4 vr[3];
    #pragma unroll
    for (int i = 0; i < 3; ++i)
        vr[i] = *(const uint4*)&Vbase[(size_t)vrow[i] * NS + (vc8[i] << 3)];

    for (int kt = 0; kt < 32; ++kt) {
        const int sk0 = kt << 6;
        const int buf = kt & 1;

        // Commit prefetched V regs to LDS
        #pragma unroll
        for (int i = 0; i < 3; ++i)
            *(uint4*)&Vs[vrow[i]][vc8[i] << 3] = vr[i];
        __syncthreads();   // (a) V staging + prior K async visible

        // adj for THIS tile -- issued first (oldest) so consuming it below
        // waits vmcnt(<=15), leaving the V/K prefetch in flight.
        int am[4][4];
        #pragma unroll
        for (int ct = 0; ct < 4; ++ct)
            #pragma unroll
            for (int r = 0; r < 4; ++r)
                am[ct][r] = adjbase[(size_t)((w << 4) + (quad << 2) + r) * NS +
                                    sk0 + (ct << 4) + nl];

        if (kt < 31) {
            const int skn = sk0 + 64;
            // V(kt+1) -> regs
            #pragma unroll
            for (int i = 0; i < 3; ++i)
                vr[i] = *(const uint4*)&Vbase[(size_t)vrow[i] * NS + skn + (vc8[i] << 3)];
            // K(kt+1) -> other LDS buffer, zero registers
            #pragma unroll
            for (int i = 0; i < 3; ++i) {
                const int cb = (i << 8) + (w << 6);
                async16(&Kbase[((size_t)skn * 12 + cb + lane) << 3],
                        &Ks[buf ^ 1][0][(size_t)cb << 3]);
            }
        }

        // Scores: 16 q x 64 kv per wave
        f4 sc[4];
        #pragma unroll
        for (int ct = 0; ct < 4; ++ct) sc[ct] = zero4;
        #pragma unroll
        for (int ct = 0; ct < 4; ++ct)
            #pragma unroll
            for (int kc = 0; kc < 3; ++kc) {
                const sh8 kf = *(const sh8*)&Ks[buf][(ct << 4) + nl][kc * 32 + (quad << 3)];
                sc[ct] = __builtin_amdgcn_mfma_f32_16x16x32_bf16(qf[kc], kf, sc[ct], 0, 0, 0);
            }

        // No-max softmax: p = adj ? 2^s : 0  (s pre-scaled by log2e/sqrt(hd))
        float pr[4][4];
        #pragma unroll
        for (int ct = 0; ct < 4; ++ct)
            #pragma unroll
            for (int r = 0; r < 4; ++r)
                pr[ct][r] = am[ct][r] ? __builtin_amdgcn_exp2f(sc[ct][r]) : 0.f;
        #pragma unroll
        for (int r = 0; r < 4; ++r)
            l_acc[r] += (pr[0][r] + pr[1][r]) + (pr[2][r] + pr[3][r]);

        // Write P as bf16 (wave-private rows; b16 writes are 2-way = free)
        const int rowbase = (w << 4) + (quad << 2);
        #pragma unroll
        for (int ct = 0; ct < 4; ++ct)
            #pragma unroll
            for (int r = 0; r < 4; ++r)
                Pb[rowbase + r][(ct << 4) + nl] = f2bf(pr[ct][r]);
        // No barrier: wave w reads back only its own rows (lgkmcnt-ordered)

        sh8 pf[2];
        #pragma unroll
        for (int kc2 = 0; kc2 < 2; ++kc2)
            pf[kc2] = *(const sh8*)&Pb[(w << 4) + nl][(kc2 << 5) + (quad << 3)];

        // PV: O[16 q][96 hd] += P[16][64] @ V[64][96]
        #pragma unroll
        for (int t = 0; t < 6; ++t)
            #pragma unroll
            for (int kc2 = 0; kc2 < 2; ++kc2) {
                const sh8 vf = *(const sh8*)&Vs[(t << 4) + nl][(kc2 << 5) + (quad << 3)];
                o[t] = __builtin_amdgcn_mfma_f32_16x16x32_bf16(pf[kc2], vf, o[t], 0, 0, 0);
            }
        __syncthreads();   // (b) all reads done; drains K/V prefetch (full-iter overlap)
    }

    // Deferred l reduction (over the 16 nl lanes of each row)
    float inv[4];
    #pragma unroll
    for (int r = 0; r < 4; ++r) {
        float l = l_acc[r];
        l += __shfl_xor(l, 1);
        l += __shfl_xor(l, 2);
        l += __shfl_xor(l, 4);
        l += __shfl_xor(l, 8);
        inv[r] = 1.0f / l;
    }

    // Epilogue: O/l + residual
    #pragma unroll
    for (int r = 0; r < 4; ++r) {
        const int srow = sq0 + (w << 4) + (quad << 2) + r;
        const size_t base = ((size_t)b * NS + srow) * ND + h * NHD;
        #pragma unroll
        for (int t = 0; t < 6; ++t) {
            const int d = (t << 4) + nl;
            out[base + d] = o[t][r] * inv[r] + features[base + d];
        }
    }
}

// ---------------------------------------------------------------------------
// Kernel 3: in-place LayerNorm over last dim (768). One wave per row.
// ---------------------------------------------------------------------------
__global__ __launch_bounds__(256) void ln_kernel(
    float* __restrict__ out, const float* __restrict__ gamma,
    const float* __restrict__ beta)
{
    const int row = (blockIdx.x << 2) + (threadIdx.x >> 6);
    const int lane = threadIdx.x & 63;
    float* p = out + (size_t)row * ND;

    float4 v[3];
    float s = 0.f, sq = 0.f;
    #pragma unroll
    for (int i = 0; i < 3; ++i) {
        v[i] = *(const float4*)&p[(i << 8) + (lane << 2)];
        s += v[i].x + v[i].y + v[i].z + v[i].w;
        sq += v[i].x * v[i].x + v[i].y * v[i].y + v[i].z * v[i].z + v[i].w * v[i].w;
    }
    #pragma unroll
    for (int off = 32; off; off >>= 1) {
        s += __shfl_xor(s, off);
        sq += __shfl_xor(sq, off);
    }
    const float mu = s * (1.0f / ND);
    const float var = sq * (1.0f / ND) - mu * mu;
    const float rs = rsqrtf(var + 1e-5f);
    #pragma unroll
    for (int i = 0; i < 3; ++i) {
        const int d = (i << 8) + (lane << 2);
        const float4 g = *(const float4*)&gamma[d];
        const float4 be = *(const float4*)&beta[d];
        float4 ov;
        ov.x = (v[i].x - mu) * rs * g.x + be.x;
        ov.y = (v[i].y - mu) * rs * g.y + be.y;
        ov.z = (v[i].z - mu) * rs * g.z + be.z;
        ov.w = (v[i].w - mu) * rs * g.w + be.w;
        *(float4*)&p[d] = ov;
    }
}

// ---------------------------------------------------------------------------
extern "C" void kernel_launch(void* const* d_in, const int* in_sizes, int n_in,
                              void* d_out, int out_size, void* d_ws, size_t ws_size,
                              hipStream_t stream) {
    (void)in_sizes; (void)n_in; (void)out_size; (void)ws_size;

    const float* features = (const float*)d_in[0];
    const int*   adj      = (const int*)d_in[1];
    const float* Wq       = (const float*)d_in[2];
    const float* bq       = (const float*)d_in[3];
    const float* Wk       = (const float*)d_in[4];
    const float* bk       = (const float*)d_in[5];
    const float* Wv       = (const float*)d_in[6];
    const float* bv       = (const float*)d_in[7];
    const float* gamma    = (const float*)d_in[8];
    const float* beta     = (const float*)d_in[9];
    float* out = (float*)d_out;

    // bf16 X and W live in d_out (fully overwritten later by attn+ln).
    __hip_bfloat16* Xb = (__hip_bfloat16*)d_out;
    __hip_bfloat16* Wb = Xb + (size_t)NX;
    // Q/K/V bf16 in workspace (V stored transposed [B,H,HD,S]).
    __hip_bfloat16* Qb = (__hip_bfloat16*)d_ws;
    __hip_bfloat16* Kb = Qb + (size_t)NX;
    __hip_bfloat16* Vb = Kb + (size_t)NX;

    // 0) fp32 -> bf16 convert (X + 3 weights)
    cvt_bf16<<<(NX + 3 * NW) / (8 * 256), 256, 0, stream>>>(
        features, Wq, Wk, Wv, Xb, Wb);

    // 1) QKV projections: grid (N/128, M/128, 3)
    dim3 g1(ND / 128, (NB * NS) / 128, 3);
    qkv_mfma<<<g1, 256, 0, stream>>>(Xb, Wb, bq, bk, bv, Qb, Kb, Vb);

    // 2) MFMA flash attention + residual: grid (S/64, H, B)
    dim3 g2(NS / 64, NH, NB);
    attn_mfma<<<g2, 256, 0, stream>>>(Qb, Kb, Vb, adj, features, out);

    // 3) LayerNorm in place
    ln_kernel<<<(NB * NS) / 4, 256, 0, stream>>>(out, gamma, beta);
}